// Round 4
// baseline (354.765 us; speedup 1.0000x reference)
//
#include <hip/hip_runtime.h>
#include <hip/hip_bf16.h>

#define PED   512
#define HDIM  64
#define EDIM  32
#define NPAIR (PED * PED)          // 262144 rows
#define GATES 256                  // 4*H
#define WF_ELEMS (16 * 64 * 24)    // W frags: [tile][lane][kstep*8+jj], bf16

typedef __attribute__((ext_vector_type(8))) __bf16 bf16x8;
typedef __attribute__((ext_vector_type(4))) float  floatx4;

__device__ __forceinline__ float sigmoidf_fast(float x) {
    return __builtin_amdgcn_rcpf(1.0f + __expf(-x));
}
__device__ __forceinline__ float tanhf_fast(float x) {
    return fmaf(2.0f, __builtin_amdgcn_rcpf(1.0f + __expf(-2.0f * x)), -1.0f);
}

__device__ __forceinline__ void stream_store(float* p, floatx4 v) {
#if __has_builtin(__builtin_nontemporal_store)
    __builtin_nontemporal_store(v, (floatx4*)p);
#else
    *(floatx4*)p = v;
#endif
}

// ---- prep: weights -> bf16 MFMA fragment order in d_ws, bias sums ----
// Fragment layout: (lane&15) -> gate index within 16-tile, (lane>>4)*8+(m&7) -> k.
// Consumed as the MFMA A operand in sra_main (operand-swapped vs the original).
__global__ void sra_prep(const float* __restrict__ W_ih, const float* __restrict__ W_hh,
                         const float* __restrict__ b_ih, const float* __restrict__ b_hh,
                         __bf16* __restrict__ Wf, float* __restrict__ bsum)
{
    int tid = blockIdx.x * 256 + threadIdx.x;
    if (tid < WF_ELEMS) {
        int m    = tid % 24;
        int nl   = tid / 24;
        int lane = nl & 63;
        int nt   = nl >> 6;
        int n = nt * 16 + (lane & 15);                       // gate index
        int k = (m >> 3) * 32 + (lane >> 4) * 8 + (m & 7);   // k index
        float w = (k < EDIM) ? W_ih[n * EDIM + k] : W_hh[n * HDIM + (k - EDIM)];
        Wf[tid] = (__bf16)w;
    }
    if (tid < GATES) bsum[tid] = b_ih[tid] + b_hh[tid];
}

// ---- main: operand-swapped MFMA => acc holds (gate = qu*4+r, pair-row = lo).
// Epilogue traffic (ct, ht_old, biases, stores) is float4 on the natural
// row-major layout: no LDS, no transposes, no scalar gather.
// Latency-bound: R2 measured best per-wave efficiency at 52 VGPR (natural
// codegen); (256,6) caps at 85 VGPR so that codegen survives while giving
// 24 waves/CU. R3 showed (256,8)'s 64-reg cap destroys it (FETCH 2x).
// cold4[] hoist: 4 extra compulsory-HBM loads in flight during MFMA phase.
__global__ __launch_bounds__(256, 6)
void sra_main(const float* __restrict__ corr,
              const float* __restrict__ ht,
              const float* __restrict__ ct,
              const int*   __restrict__ nei,
              const float* __restrict__ W_emb,
              const float* __restrict__ b_emb,
              const __bf16* __restrict__ Wf,
              const float* __restrict__ bsumg,
              float* __restrict__ h_out,
              float* __restrict__ c_out)
{
    const int tid  = threadIdx.x;
    const int lane = tid & 63;
    const int lo   = lane & 15;
    const int qu   = lane >> 4;

    const int tile = blockIdx.x * 4 + (tid >> 6);
    const int row  = tile * 16 + lo;                 // this lane's pair-row
    const size_t rowoff = (size_t)row * HDIM;

    // ---- compulsory HBM streams issued first: ct (all 4 groups) + corr + ht
    floatx4 cold4[4];
#pragma unroll
    for (int g = 0; g < 4; ++g)
        cold4[g] = *(const floatx4*)(ct + rowoff + g * 16 + qu * 4);

    const float2 xy = *(const float2*)(corr + (size_t)row * 2);

    // ---- h B-frags (k 32..95): full-line float4 loads, row lo ----
    const floatx4 h0a = *(const floatx4*)(ht + rowoff + qu * 8);
    const floatx4 h0b = *(const floatx4*)(ht + rowoff + qu * 8 + 4);
    const floatx4 h1a = *(const floatx4*)(ht + rowoff + 32 + qu * 8);
    const floatx4 h1b = *(const floatx4*)(ht + rowoff + 32 + qu * 8 + 4);

    // ---- x B-frag (k 0..31): embedding + ReLU, computed in-register ----
    bf16x8 b0;
#pragma unroll
    for (int j = 0; j < 8; ++j) {
        const int e = qu * 8 + j;
        float v = fmaf(xy.x, W_emb[e * 2 + 0], fmaf(xy.y, W_emb[e * 2 + 1], b_emb[e]));
        b0[j] = (__bf16)fmaxf(v, 0.0f);
    }

    bf16x8 b1, b2;
#pragma unroll
    for (int j = 0; j < 4; ++j) {
        b1[j]     = (__bf16)h0a[j];
        b1[j + 4] = (__bf16)h0b[j];
        b2[j]     = (__bf16)h1a[j];
        b2[j + 4] = (__bf16)h1b[j];
    }

    const bool msk = nei[row] > 0;                   // lane-uniform mask
    const __bf16* bbase = Wf + lane * 24;

    // ---- 4 gate-quad groups; per group: vector epilogue loads in flight
    // over 12 MFMAs, then float4 stores straight to global ----
#pragma unroll
    for (int g = 0; g < 4; ++g) {
        const int kb = g * 16 + qu * 4;              // gate sub-index [0,64)

        const floatx4 cold = cold4[g];
        const floatx4 hold = *(const floatx4*)(ht + rowoff + kb);   // L1-hot
        const floatx4 bi4  = *(const floatx4*)(bsumg + kb);
        const floatx4 bf4  = *(const floatx4*)(bsumg + 64 + kb);
        const floatx4 bg4  = *(const floatx4*)(bsumg + 128 + kb);
        const floatx4 bo4  = *(const floatx4*)(bsumg + 192 + kb);

        const __bf16* pi = bbase + (g     ) * 1536;
        const __bf16* pf = bbase + (g +  4) * 1536;
        const __bf16* pg = bbase + (g +  8) * 1536;
        const __bf16* po = bbase + (g + 12) * 1536;

        const bf16x8 wi0 = *(const bf16x8*)(pi);
        const bf16x8 wi1 = *(const bf16x8*)(pi + 8);
        const bf16x8 wi2 = *(const bf16x8*)(pi + 16);
        const bf16x8 wf0 = *(const bf16x8*)(pf);
        const bf16x8 wf1 = *(const bf16x8*)(pf + 8);
        const bf16x8 wf2 = *(const bf16x8*)(pf + 16);
        const bf16x8 wg0 = *(const bf16x8*)(pg);
        const bf16x8 wg1 = *(const bf16x8*)(pg + 8);
        const bf16x8 wg2 = *(const bf16x8*)(pg + 16);
        const bf16x8 wo0 = *(const bf16x8*)(po);
        const bf16x8 wo1 = *(const bf16x8*)(po + 8);
        const bf16x8 wo2 = *(const bf16x8*)(po + 16);

        const floatx4 z = {0.f, 0.f, 0.f, 0.f};
        floatx4 ai = __builtin_amdgcn_mfma_f32_16x16x32_bf16(wi0, b0, z, 0, 0, 0);
        floatx4 af = __builtin_amdgcn_mfma_f32_16x16x32_bf16(wf0, b0, z, 0, 0, 0);
        floatx4 ag = __builtin_amdgcn_mfma_f32_16x16x32_bf16(wg0, b0, z, 0, 0, 0);
        floatx4 ao = __builtin_amdgcn_mfma_f32_16x16x32_bf16(wo0, b0, z, 0, 0, 0);
        ai = __builtin_amdgcn_mfma_f32_16x16x32_bf16(wi1, b1, ai, 0, 0, 0);
        af = __builtin_amdgcn_mfma_f32_16x16x32_bf16(wf1, b1, af, 0, 0, 0);
        ag = __builtin_amdgcn_mfma_f32_16x16x32_bf16(wg1, b1, ag, 0, 0, 0);
        ao = __builtin_amdgcn_mfma_f32_16x16x32_bf16(wo1, b1, ao, 0, 0, 0);
        ai = __builtin_amdgcn_mfma_f32_16x16x32_bf16(wi2, b2, ai, 0, 0, 0);
        af = __builtin_amdgcn_mfma_f32_16x16x32_bf16(wf2, b2, af, 0, 0, 0);
        ag = __builtin_amdgcn_mfma_f32_16x16x32_bf16(wg2, b2, ag, 0, 0, 0);
        ao = __builtin_amdgcn_mfma_f32_16x16x32_bf16(wo2, b2, ao, 0, 0, 0);

        floatx4 cn4, hn4;
#pragma unroll
        for (int r = 0; r < 4; ++r) {
            const float iv = sigmoidf_fast(ai[r] + bi4[r]);
            const float fv = sigmoidf_fast(af[r] + bf4[r]);
            const float gv = tanhf_fast(ag[r] + bg4[r]);
            const float ov = sigmoidf_fast(ao[r] + bo4[r]);
            const float cn = fv * cold[r] + iv * gv;
            const float hn = ov * tanhf_fast(cn);
            cn4[r] = msk ? cn : cold[r];
            hn4[r] = msk ? hn : hold[r];
        }
        // streaming outputs, never re-read
        stream_store(c_out + rowoff + kb, cn4);
        stream_store(h_out + rowoff + kb, hn4);
    }
}

extern "C" void kernel_launch(void* const* d_in, const int* in_sizes, int n_in,
                              void* d_out, int out_size, void* d_ws, size_t ws_size,
                              hipStream_t stream) {
    const float* corr  = (const float*)d_in[0];
    const float* ht    = (const float*)d_in[1];
    const float* ct    = (const float*)d_in[2];
    const int*   nei   = (const int*)  d_in[3];
    const float* W_emb = (const float*)d_in[4];
    const float* b_emb = (const float*)d_in[5];
    const float* W_ih  = (const float*)d_in[6];
    const float* W_hh  = (const float*)d_in[7];
    const float* b_ih  = (const float*)d_in[8];
    const float* b_hh  = (const float*)d_in[9];

    __bf16* Wf   = (__bf16*)d_ws;                        // 49152 B
    float*  bsum = (float*)((char*)d_ws + WF_ELEMS * 2); // 1024 B

    float* hout = (float*)d_out;
    float* cout = hout + (size_t)NPAIR * HDIM;

    hipLaunchKernelGGL(sra_prep, dim3(96), dim3(256), 0, stream,
                       W_ih, W_hh, b_ih, b_hh, Wf, bsum);
    hipLaunchKernelGGL(sra_main, dim3(NPAIR / 64), dim3(256), 0, stream,
                       corr, ht, ct, nei, W_emb, b_emb, Wf, bsum, hout, cout);
}

// Round 5
// 282.100 us; speedup vs baseline: 1.2576x; 1.2576x over previous
//
#include <hip/hip_runtime.h>
#include <hip/hip_bf16.h>

#define PED   512
#define HDIM  64
#define EDIM  32
#define NPAIR (PED * PED)          // 262144 rows
#define GATES 256                  // 4*H
#define WF_ELEMS (48 * 64 * 8)     // W frags: [slot][lane][j], slot=(gate_tile*3+ks)

typedef __attribute__((ext_vector_type(8))) __bf16 bf16x8;
typedef __attribute__((ext_vector_type(4))) float  floatx4;

__device__ __forceinline__ float sigmoidf_fast(float x) {
    return __builtin_amdgcn_rcpf(1.0f + __expf(-x));
}
__device__ __forceinline__ float tanhf_fast(float x) {
    return fmaf(2.0f, __builtin_amdgcn_rcpf(1.0f + __expf(-2.0f * x)), -1.0f);
}

// ---- prep: weights -> bf16 MFMA A-fragments, LANE-CONTIGUOUS slot layout ----
// Wf[((gate_tile*3 + ks)*64 + lane)*8 + j] = W[gate_tile*16 + (lane&15)]
//                                             [ks*32 + (lane>>4)*8 + j]
// => every 64-lane 16B read (global stage AND ds_read_b128) is contiguous:
//    16 lines/instr instead of 48 with the old 48B-stride layout.
__global__ void sra_prep(const float* __restrict__ W_ih, const float* __restrict__ W_hh,
                         const float* __restrict__ b_ih, const float* __restrict__ b_hh,
                         __bf16* __restrict__ Wf, float* __restrict__ bsum)
{
    int tid = blockIdx.x * 256 + threadIdx.x;
    if (tid < WF_ELEMS) {
        int j    = tid & 7;
        int lane = (tid >> 3) & 63;
        int s    = tid >> 9;                    // slot 0..47
        int nt   = s / 3;                       // gate tile 0..15
        int ks   = s - nt * 3;                  // k-step 0..2
        int n = nt * 16 + (lane & 15);          // gate index
        int k = ks * 32 + (lane >> 4) * 8 + j;  // k index
        float w = (k < EDIM) ? W_ih[n * EDIM + k] : W_hh[n * HDIM + (k - EDIM)];
        Wf[tid] = (__bf16)w;
    }
    if (tid < GATES) bsum[tid] = b_ih[tid] + b_hh[tid];
}

// ---- main: weight table staged to LDS once per block; all per-row traffic
// is ~28 fully-coalesced VMEM instrs/wave. Swapped-operand MFMA (weights=A
// from LDS, x/h=B in regs) => acc (gate=qu*4+r, row=lo), float4 epilogue,
// no transposes. 512 thr (8 waves) x 48KB LDS -> 3 blocks/CU, 24 waves/CU.
__global__ __launch_bounds__(512, 6)
void sra_main(const float* __restrict__ corr,
              const float* __restrict__ ht,
              const float* __restrict__ ct,
              const int*   __restrict__ nei,
              const float* __restrict__ W_emb,
              const float* __restrict__ b_emb,
              const __bf16* __restrict__ Wf,
              const float* __restrict__ bsumg,
              float* __restrict__ h_out,
              float* __restrict__ c_out)
{
    __shared__ __align__(16) __bf16 shw[WF_ELEMS];   // 48 KB
    __shared__ float shb[GATES];                     // 1 KB

    const int tid  = threadIdx.x;
    const int wave = tid >> 6;
    const int lane = tid & 63;
    const int lo   = lane & 15;
    const int qu   = lane >> 4;

    // ---- stage weight table (L2-hot) into LDS: 3072 x 16B, lane-contiguous
    {
        const floatx4* src = (const floatx4*)Wf;
        floatx4*       dst = (floatx4*)shw;
#pragma unroll
        for (int it = 0; it < 6; ++it)
            dst[it * 512 + tid] = src[it * 512 + tid];
        if (tid < GATES) shb[tid] = bsumg[tid];
    }

    const int tile = blockIdx.x * 8 + wave;
    const int row  = tile * 16 + lo;                 // this lane's pair-row
    const size_t rowoff = (size_t)row * HDIM;

    // ---- per-row global loads issued before the barrier (overlap staging)
    const float2 xy = *(const float2*)(corr + (size_t)row * 2);
    const floatx4 h0a = *(const floatx4*)(ht + rowoff + qu * 8);
    const floatx4 h0b = *(const floatx4*)(ht + rowoff + qu * 8 + 4);
    const floatx4 h1a = *(const floatx4*)(ht + rowoff + 32 + qu * 8);
    const floatx4 h1b = *(const floatx4*)(ht + rowoff + 32 + qu * 8 + 4);
    const bool msk = nei[row] > 0;                   // lane-uniform mask

    // ---- x B-frag (k 0..31): embedding + ReLU, in-register ----
    bf16x8 b0;
#pragma unroll
    for (int j = 0; j < 8; ++j) {
        const int e = qu * 8 + j;
        float v = fmaf(xy.x, W_emb[e * 2 + 0], fmaf(xy.y, W_emb[e * 2 + 1], b_emb[e]));
        b0[j] = (__bf16)fmaxf(v, 0.0f);
    }
    // ---- h B-frags (k 32..95) ----
    bf16x8 b1, b2;
#pragma unroll
    for (int j = 0; j < 4; ++j) {
        b1[j]     = (__bf16)h0a[j];
        b1[j + 4] = (__bf16)h0b[j];
        b2[j]     = (__bf16)h1a[j];
        b2[j + 4] = (__bf16)h1b[j];
    }

    __syncthreads();

    const bf16x8* wp = (const bf16x8*)shw;           // [slot][lane] 16B frags

    // ---- 4 gate-quad groups: 12 ds_read_b128 + 12 MFMA + float4 epilogue ----
#pragma unroll
    for (int g = 0; g < 4; ++g) {
        const int kb = g * 16 + qu * 4;              // gate sub-index [0,64)

        const floatx4 cold = *(const floatx4*)(ct + rowoff + kb);
        const floatx4 hold = *(const floatx4*)(ht + rowoff + kb);   // L1-hot
        const floatx4 bi4  = *(const floatx4*)(shb + kb);
        const floatx4 bf4  = *(const floatx4*)(shb + 64 + kb);
        const floatx4 bg4  = *(const floatx4*)(shb + 128 + kb);
        const floatx4 bo4  = *(const floatx4*)(shb + 192 + kb);

        const bf16x8 wi0 = wp[((g     ) * 3 + 0) * 64 + lane];
        const bf16x8 wi1 = wp[((g     ) * 3 + 1) * 64 + lane];
        const bf16x8 wi2 = wp[((g     ) * 3 + 2) * 64 + lane];
        const bf16x8 wf0 = wp[((g +  4) * 3 + 0) * 64 + lane];
        const bf16x8 wf1 = wp[((g +  4) * 3 + 1) * 64 + lane];
        const bf16x8 wf2 = wp[((g +  4) * 3 + 2) * 64 + lane];
        const bf16x8 wg0 = wp[((g +  8) * 3 + 0) * 64 + lane];
        const bf16x8 wg1 = wp[((g +  8) * 3 + 1) * 64 + lane];
        const bf16x8 wg2 = wp[((g +  8) * 3 + 2) * 64 + lane];
        const bf16x8 wo0 = wp[((g + 12) * 3 + 0) * 64 + lane];
        const bf16x8 wo1 = wp[((g + 12) * 3 + 1) * 64 + lane];
        const bf16x8 wo2 = wp[((g + 12) * 3 + 2) * 64 + lane];

        const floatx4 z = {0.f, 0.f, 0.f, 0.f};
        floatx4 ai = __builtin_amdgcn_mfma_f32_16x16x32_bf16(wi0, b0, z, 0, 0, 0);
        floatx4 af = __builtin_amdgcn_mfma_f32_16x16x32_bf16(wf0, b0, z, 0, 0, 0);
        floatx4 ag = __builtin_amdgcn_mfma_f32_16x16x32_bf16(wg0, b0, z, 0, 0, 0);
        floatx4 ao = __builtin_amdgcn_mfma_f32_16x16x32_bf16(wo0, b0, z, 0, 0, 0);
        ai = __builtin_amdgcn_mfma_f32_16x16x32_bf16(wi1, b1, ai, 0, 0, 0);
        af = __builtin_amdgcn_mfma_f32_16x16x32_bf16(wf1, b1, af, 0, 0, 0);
        ag = __builtin_amdgcn_mfma_f32_16x16x32_bf16(wg1, b1, ag, 0, 0, 0);
        ao = __builtin_amdgcn_mfma_f32_16x16x32_bf16(wo1, b1, ao, 0, 0, 0);
        ai = __builtin_amdgcn_mfma_f32_16x16x32_bf16(wi2, b2, ai, 0, 0, 0);
        af = __builtin_amdgcn_mfma_f32_16x16x32_bf16(wf2, b2, af, 0, 0, 0);
        ag = __builtin_amdgcn_mfma_f32_16x16x32_bf16(wg2, b2, ag, 0, 0, 0);
        ao = __builtin_amdgcn_mfma_f32_16x16x32_bf16(wo2, b2, ao, 0, 0, 0);

        floatx4 cn4, hn4;
#pragma unroll
        for (int r = 0; r < 4; ++r) {
            const float iv = sigmoidf_fast(ai[r] + bi4[r]);
            const float fv = sigmoidf_fast(af[r] + bf4[r]);
            const float gv = tanhf_fast(ag[r] + bg4[r]);
            const float ov = sigmoidf_fast(ao[r] + bo4[r]);
            const float cn = fv * cold[r] + iv * gv;
            const float hn = ov * tanhf_fast(cn);
            cn4[r] = msk ? cn : cold[r];
            hn4[r] = msk ? hn : hold[r];
        }
        *(floatx4*)(c_out + rowoff + kb) = cn4;      // plain stores (nt hurt: R4)
        *(floatx4*)(h_out + rowoff + kb) = hn4;
    }
}

extern "C" void kernel_launch(void* const* d_in, const int* in_sizes, int n_in,
                              void* d_out, int out_size, void* d_ws, size_t ws_size,
                              hipStream_t stream) {
    const float* corr  = (const float*)d_in[0];
    const float* ht    = (const float*)d_in[1];
    const float* ct    = (const float*)d_in[2];
    const int*   nei   = (const int*)  d_in[3];
    const float* W_emb = (const float*)d_in[4];
    const float* b_emb = (const float*)d_in[5];
    const float* W_ih  = (const float*)d_in[6];
    const float* W_hh  = (const float*)d_in[7];
    const float* b_ih  = (const float*)d_in[8];
    const float* b_hh  = (const float*)d_in[9];

    __bf16* Wf   = (__bf16*)d_ws;                        // 49152 B
    float*  bsum = (float*)((char*)d_ws + WF_ELEMS * 2); // 1024 B

    float* hout = (float*)d_out;
    float* cout = hout + (size_t)NPAIR * HDIM;

    hipLaunchKernelGGL(sra_prep, dim3(96), dim3(256), 0, stream,
                       W_ih, W_hh, b_ih, b_hh, Wf, bsum);
    hipLaunchKernelGGL(sra_main, dim3(NPAIR / 128), dim3(512), 0, stream,
                       corr, ht, ct, nei, W_emb, b_emb, Wf, bsum, hout, cout);
}